// Round 1
// baseline (664.026 us; speedup 1.0000x reference)
//
#include <hip/hip_runtime.h>
#include <cstddef>

// Problem constants
#define NB 16
#define NVOX 128
#define VOL_PER_B (NVOX * NVOX * NVOX)   // 2097152
#define TOTVOX (NB * VOL_PER_B)          // 33554432
#define NPT 1920

static __device__ __forceinline__ float2 f2(float a, float b) {
    float2 r; r.x = a; r.y = b; return r;
}

// ---------------------------------------------------------------------------
// Fused MLP + trilinear splat.
// One block per batch (16 blocks, 256 threads). All activations live in LDS.
// Splats (val*w) and (w) into interleaved float2 accumulator via atomics.
// ---------------------------------------------------------------------------
__global__ __launch_bounds__(256)
void mlp_splat(const float* __restrict__ q, const float* __restrict__ qval,
               const float* __restrict__ w1, const float* __restrict__ b1,
               const float* __restrict__ w2, const float* __restrict__ b2,
               const float* __restrict__ w3, const float* __restrict__ b3,
               const float* __restrict__ w4, const float* __restrict__ b4,
               const float* __restrict__ w5, const float* __restrict__ b5,
               float2* __restrict__ acc)
{
    __shared__ float qs[2048];     // input row
    __shared__ float bufA[7680];   // x1 (1920) then x3 (7680)
    __shared__ float bufC[3840];   // x2
    __shared__ float meanv[64], rstdv[64];
    __shared__ float m4[16], r4[16];

    const int b = blockIdx.x;
    const int t = threadIdx.x;

    const float* qb = q + b * 2048;
    for (int u = t; u < 2048; u += 256) qs[u] = qb[u];
    __syncthreads();

    // stage1: x1[o,l] = b1[o] + sum_i w1[o,i] * q[i*8+l]   (240x8 = 1920)
    for (int k = t; k < 1920; k += 256) {
        int o = k >> 3, l = k & 7;
        const float* wrow = w1 + o * 256;
        float s = b1[o];
        #pragma unroll 8
        for (int i = 0; i < 256; ++i) s = fmaf(wrow[i], qs[i * 8 + l], s);
        bufA[k] = s;
    }
    __syncthreads();
    // IN over view (64, 30)
    if (t < 64) {
        float s = 0.f, s2 = 0.f;
        for (int p = 0; p < 30; ++p) { float v = bufA[t * 30 + p]; s += v; s2 += v * v; }
        float m = s * (1.f / 30.f);
        float var = s2 * (1.f / 30.f) - m * m;
        meanv[t] = m; rstdv[t] = rsqrtf(var + 1e-5f);
    }
    __syncthreads();
    for (int k = t; k < 1920; k += 256) {
        int c = k / 30;
        bufA[k] = fmaxf((bufA[k] - meanv[c]) * rstdv[c], 0.f);
    }
    __syncthreads();

    // stage2: grouped conv 64->128: flat m = c*60 + j*30 + p (3840)
    for (int m = t; m < 3840; m += 256) {
        int c = m / 60;
        int r = m - c * 60;
        int j = r / 30;
        int p = r - j * 30;
        bufC[m] = fmaf(bufA[c * 30 + p], w2[c * 2 + j], b2[c * 2 + j]);
    }
    __syncthreads();
    // IN over view (32, 120)
    if (t < 32) {
        float s = 0.f, s2 = 0.f;
        for (int p = 0; p < 120; ++p) { float v = bufC[t * 120 + p]; s += v; s2 += v * v; }
        float m = s * (1.f / 120.f);
        float var = s2 * (1.f / 120.f) - m * m;
        meanv[t] = m; rstdv[t] = rsqrtf(var + 1e-5f);
    }
    __syncthreads();
    for (int m = t; m < 3840; m += 256) {
        int c = m / 120;
        bufC[m] = fmaxf((bufC[m] - meanv[c]) * rstdv[c], 0.f);
    }
    __syncthreads();

    // stage3: grouped conv 32->64: flat m = c*240 + j*120 + p (7680)
    for (int m = t; m < 7680; m += 256) {
        int c = m / 240;
        int r = m - c * 240;
        int j = r / 120;
        int p = r - j * 120;
        bufA[m] = fmaf(bufC[c * 120 + p], w3[c * 2 + j], b3[c * 2 + j]);
    }
    __syncthreads();
    // IN over view (16, 480)
    if (t < 16) {
        float s = 0.f, s2 = 0.f;
        for (int p = 0; p < 480; ++p) { float v = bufA[t * 480 + p]; s += v; s2 += v * v; }
        float m = s * (1.f / 480.f);
        float var = s2 * (1.f / 480.f) - m * m;
        meanv[t] = m; rstdv[t] = rsqrtf(var + 1e-5f);
    }
    __syncthreads();
    for (int m = t; m < 7680; m += 256) {
        int c = m / 480;
        bufA[m] = fmaxf((bufA[m] - meanv[c]) * rstdv[c], 0.f);
    }
    __syncthreads();

    // stage4 IN stats computed analytically from x3n channel sums:
    // x4[c, j*480+p] = x3n[c,p]*w4[c,j] + b4[c*4+j]
    if (t < 16) {
        float s = 0.f, s2 = 0.f;
        for (int p = 0; p < 480; ++p) { float v = bufA[t * 480 + p]; s += v; s2 += v * v; }
        float sum4 = 0.f, sq4 = 0.f;
        for (int j = 0; j < 4; ++j) {
            float w = w4[t * 4 + j], bb = b4[t * 4 + j];
            sum4 += w * s + 480.f * bb;
            sq4  += w * w * s2 + 2.f * w * bb * s + 480.f * bb * bb;
        }
        float m = sum4 * (1.f / 1920.f);
        float var = sq4 * (1.f / 1920.f) - m * m;
        m4[t] = m; r4[t] = rsqrtf(var + 1e-5f);
    }
    __syncthreads();

    // per-point: stage4 apply + stage5 einsum + tanh + trilinear splat
    for (int l = t; l < NPT; l += 256) {
        int j = l / 480;
        int p = l - j * 480;
        float a0 = b5[0], a1 = b5[1], a2 = b5[2];
        #pragma unroll
        for (int c = 0; c < 16; ++c) {
            float xv = bufA[c * 480 + p];
            float x4 = fmaf(xv, w4[c * 4 + j], b4[c * 4 + j]);
            float h  = fmaxf((x4 - m4[c]) * r4[c], 0.f);
            a0 = fmaf(w5[c],      h, a0);
            a1 = fmaf(w5[16 + c], h, a1);
            a2 = fmaf(w5[32 + c], h, a2);
        }
        // grid[..,0]=x, grid[..,1]=y, grid[..,2]=z ; p = tanh(a)*64 + 63.5
        float px = tanhf(a0) * 64.f + 63.5f;
        float py = tanhf(a1) * 64.f + 63.5f;
        float pz = tanhf(a2) * 64.f + 63.5f;
        float val = 1.f / (1.f + expf(-qval[l]));

        float x0f = floorf(px), y0f = floorf(py), z0f = floorf(pz);
        float fx = px - x0f, fy = py - y0f, fz = pz - z0f;
        int x0 = (int)x0f, y0 = (int)y0f, z0 = (int)z0f;
        for (int dz = 0; dz < 2; ++dz) {
            int zi = z0 + dz;
            if (zi < 0 || zi >= NVOX) continue;
            float wz = dz ? fz : 1.f - fz;
            for (int dy = 0; dy < 2; ++dy) {
                int yi = y0 + dy;
                if (yi < 0 || yi >= NVOX) continue;
                float wy = dy ? fy : 1.f - fy;
                for (int dx = 0; dx < 2; ++dx) {
                    int xi = x0 + dx;
                    if (xi < 0 || xi >= NVOX) continue;
                    float wx = dx ? fx : 1.f - fx;
                    float w = wx * wy * wz;
                    int idx = ((b * NVOX + zi) * NVOX + yi) * NVOX + xi;
                    atomicAdd(&acc[idx].x, w * val);
                    atomicAdd(&acc[idx].y, w);
                }
            }
        }
    }
}

// ---------------------------------------------------------------------------
// Composed smoothing: avgpool3(3x,pad=1,count_include_pad) applied 3x per axis
// == per-axis 7-tap [1,3,6,7,6,3,1]/27 with boundary rows (from A^3, A = zero-
// padded 3-tap average):  row0=[4,5,3,1]/27, row1=[5,7,6,3,1]/27, symmetric on
// the right. Rolling register window; threads coalesced along x.
// ---------------------------------------------------------------------------
__device__ __forceinline__ float2 w7(float2 v0, float2 v1, float2 v2, float2 v3,
                                     float2 v4, float2 v5, float2 v6,
                                     float cm1, float c0, float cp1)
{
    float sx = (v0.x + v6.x) + 3.f * (v1.x + v5.x) + cm1 * v2.x + c0 * v3.x + cp1 * v4.x;
    float sy = (v0.y + v6.y) + 3.f * (v1.y + v5.y) + cm1 * v2.y + c0 * v3.y + cp1 * v4.y;
    return f2(sx * (1.f / 27.f), sy * (1.f / 27.f));
}

template <int HI_STRIDE, int AX>
__global__ __launch_bounds__(256)
void smooth_pass(const float2* __restrict__ in, float2* __restrict__ out)
{
    int T = blockIdx.x * 256 + threadIdx.x;   // 262144 threads total
    int b = T >> 14;
    int r = T & 16383;
    int hi = r >> 7, lo = r & 127;
    int base = b * VOL_PER_B + hi * HI_STRIDE + lo;
    const float2* ip = in + base;
    float2* op = out + base;

    const float2 z = f2(0.f, 0.f);
    float2 v0 = z, v1 = z, v2 = z, v3, v4, v5;
    v3 = ip[0]; v4 = ip[AX]; v5 = ip[2 * AX];

    // i = 0,1 (left boundary weights)
    {
        float2 a  = ip[3 * AX];
        float2 bb = ip[4 * AX];
        op[0]  = w7(v0, v1, v2, v3, v4, v5, a, 6.f, 4.f, 5.f);
        op[AX] = w7(v1, v2, v3, v4, v5, a, bb, 5.f, 7.f, 6.f);
        v0 = v2; v1 = v3; v2 = v4; v3 = v5; v4 = a; v5 = bb;
    }
    // interior, unconditional loads: i = 2..122 (loads up to ip[126])
    #pragma unroll 4
    for (int i = 2; i < 124; i += 2) {
        float2 a  = ip[(i + 3) * AX];
        float2 bb = ip[(i + 4) * AX];
        op[i * AX]       = w7(v0, v1, v2, v3, v4, v5, a, 6.f, 7.f, 6.f);
        op[(i + 1) * AX] = w7(v1, v2, v3, v4, v5, a, bb, 6.f, 7.f, 6.f);
        v0 = v2; v1 = v3; v2 = v4; v3 = v5; v4 = a; v5 = bb;
    }
    // i = 124,125 (load 127 valid, 128 OOB)
    {
        float2 a  = ip[127 * AX];
        float2 bb = z;
        op[124 * AX] = w7(v0, v1, v2, v3, v4, v5, a, 6.f, 7.f, 6.f);
        op[125 * AX] = w7(v1, v2, v3, v4, v5, a, bb, 6.f, 7.f, 6.f);
        v0 = v2; v1 = v3; v2 = v4; v3 = v5; v4 = a; v5 = bb;
    }
    // i = 126,127 (right boundary weights; v5,a,bb already zero)
    {
        float2 a = z, bb = z;
        op[126 * AX] = w7(v0, v1, v2, v3, v4, v5, a, 6.f, 7.f, 5.f);
        op[127 * AX] = w7(v1, v2, v3, v4, v5, a, bb, 5.f, 4.f, 6.f);
    }
}

// ---------------------------------------------------------------------------
// X-axis pass (contiguous) fused with the final division.
// Block = 256 threads = 2 lines of 128, staged in LDS with 3-wide zero pads.
// ---------------------------------------------------------------------------
__global__ __launch_bounds__(256)
void smooth_x_div(const float2* __restrict__ in, float* __restrict__ out)
{
    __shared__ float2 line[2][134];
    int ly = threadIdx.x >> 7;
    int tx = threadIdx.x & 127;
    int line_id = blockIdx.x * 2 + ly;       // 0 .. 262143  (= b*128*128 + z*128 + y)
    int base = line_id * 128;

    line[ly][3 + tx] = in[base + tx];
    if (tx < 3) {
        line[ly][tx] = f2(0.f, 0.f);
        line[ly][131 + tx] = f2(0.f, 0.f);
    }
    __syncthreads();

    const float2* L = &line[ly][3 + tx];
    float cm1 = 6.f, c0 = 7.f, cp1 = 6.f;
    if (tx == 0)        { c0 = 4.f; cp1 = 5.f; }
    else if (tx == 1)   { cm1 = 5.f; }
    else if (tx == 126) { cp1 = 5.f; }
    else if (tx == 127) { c0 = 4.f; cm1 = 5.f; }

    float sa = (L[-3].x + L[3].x) + 3.f * (L[-2].x + L[2].x)
             + cm1 * L[-1].x + c0 * L[0].x + cp1 * L[1].x;
    float sb = (L[-3].y + L[3].y) + 3.f * (L[-2].y + L[2].y)
             + cm1 * L[-1].y + c0 * L[0].y + cp1 * L[1].y;
    sa *= (1.f / 27.f);
    sb *= (1.f / 27.f);
    out[base + tx] = sa / (sb + 0.001f);
}

// ---------------------------------------------------------------------------
extern "C" void kernel_launch(void* const* d_in, const int* in_sizes, int n_in,
                              void* d_out, int out_size, void* d_ws, size_t ws_size,
                              hipStream_t stream)
{
    const float* q    = (const float*)d_in[0];
    const float* qval = (const float*)d_in[1];
    const float* w1   = (const float*)d_in[2];
    const float* b1   = (const float*)d_in[3];
    const float* w2   = (const float*)d_in[4];
    const float* b2   = (const float*)d_in[5];
    const float* w3   = (const float*)d_in[6];
    const float* b3   = (const float*)d_in[7];
    const float* w4   = (const float*)d_in[8];
    const float* b4   = (const float*)d_in[9];
    const float* w5   = (const float*)d_in[10];
    const float* b5   = (const float*)d_in[11];
    float* out = (float*)d_out;

    // ws layout: buf0 (interleaved {out,out0}, 268 MB) | buf1 (268 MB)
    float2* buf0 = (float2*)d_ws;
    float2* buf1 = buf0 + (size_t)TOTVOX;

    hipMemsetAsync(buf0, 0, (size_t)TOTVOX * sizeof(float2), stream);

    mlp_splat<<<NB, 256, 0, stream>>>(q, qval, w1, b1, w2, b2, w3, b3,
                                      w4, b4, w5, b5, buf0);

    // z-axis: fixed (y,x), stride 128*128
    smooth_pass<128, 16384><<<TOTVOX / (128 * 256), 256, 0, stream>>>(buf0, buf1);
    // y-axis: fixed (z,x), stride 128
    smooth_pass<16384, 128><<<TOTVOX / (128 * 256), 256, 0, stream>>>(buf1, buf0);
    // x-axis + division
    smooth_x_div<<<TOTVOX / 256, 256, 0, stream>>>(buf0, out);
}

// Round 2
// 600.272 us; speedup vs baseline: 1.1062x; 1.1062x over previous
//
#include <hip/hip_runtime.h>
#include <cstddef>

// Problem constants
#define NB 16
#define NVOX 128
#define VOL_PER_B (NVOX * NVOX * NVOX)   // 2097152
#define TOTVOX (NB * VOL_PER_B)          // 33554432
#define NPT 1920

static __device__ __forceinline__ float2 f2(float a, float b) {
    float2 r; r.x = a; r.y = b; return r;
}

// ---------------------------------------------------------------------------
// Fused MLP + trilinear splat. One block per batch, 1024 threads.
// Stage 1 vectorized: float4 loads of w1 (global) and transposed q (LDS).
// ---------------------------------------------------------------------------
__global__ __launch_bounds__(1024)
void mlp_splat(const float* __restrict__ q, const float* __restrict__ qval,
               const float* __restrict__ w1, const float* __restrict__ b1,
               const float* __restrict__ w2, const float* __restrict__ b2,
               const float* __restrict__ w3, const float* __restrict__ b3,
               const float* __restrict__ w4, const float* __restrict__ b4,
               const float* __restrict__ w5, const float* __restrict__ b5,
               float2* __restrict__ acc)
{
    __shared__ __align__(16) float qsT[8 * 260];  // transposed q, padded stride (bank-spread)
    __shared__ float bufA[7680];   // x1 (1920) then x3 (7680)
    __shared__ float bufC[3840];   // x2
    __shared__ float meanv[64], rstdv[64];
    __shared__ float m4[16], r4[16];

    const int b = blockIdx.x;
    const int t = threadIdx.x;

    const float* qb = q + b * 2048;
    for (int u = t; u < 2048; u += 1024) {
        // x[i,l] = q[i*8+l]  ->  qsT[l*260 + i]
        int i = u >> 3, l = u & 7;
        qsT[l * 260 + i] = qb[u];
    }
    __syncthreads();

    // stage1: x1[o,l] = b1[o] + sum_i w1[o,i] * qT[l,i]   (240x8 = 1920)
    for (int k = t; k < 1920; k += 1024) {
        int o = k >> 3, l = k & 7;
        const float4* wrow = (const float4*)(w1 + o * 256);
        const float4* xrow = (const float4*)(&qsT[l * 260]);
        float s0 = b1[o], s1 = 0.f, s2 = 0.f, s3 = 0.f;
        #pragma unroll 8
        for (int i = 0; i < 64; ++i) {
            float4 w = wrow[i];
            float4 x = xrow[i];
            s0 = fmaf(w.x, x.x, s0);
            s1 = fmaf(w.y, x.y, s1);
            s2 = fmaf(w.z, x.z, s2);
            s3 = fmaf(w.w, x.w, s3);
        }
        bufA[k] = (s0 + s1) + (s2 + s3);
    }
    __syncthreads();
    // IN over view (64, 30)
    if (t < 64) {
        float s = 0.f, s2 = 0.f;
        for (int p = 0; p < 30; ++p) { float v = bufA[t * 30 + p]; s += v; s2 += v * v; }
        float m = s * (1.f / 30.f);
        float var = s2 * (1.f / 30.f) - m * m;
        meanv[t] = m; rstdv[t] = rsqrtf(var + 1e-5f);
    }
    __syncthreads();
    for (int k = t; k < 1920; k += 1024) {
        int c = k / 30;
        bufA[k] = fmaxf((bufA[k] - meanv[c]) * rstdv[c], 0.f);
    }
    __syncthreads();

    // stage2: grouped conv 64->128: flat m = c*60 + j*30 + p (3840)
    for (int m = t; m < 3840; m += 1024) {
        int c = m / 60;
        int r = m - c * 60;
        int j = r / 30;
        int p = r - j * 30;
        bufC[m] = fmaf(bufA[c * 30 + p], w2[c * 2 + j], b2[c * 2 + j]);
    }
    __syncthreads();
    // IN over view (32, 120)
    if (t < 32) {
        float s = 0.f, s2 = 0.f;
        for (int p = 0; p < 120; ++p) { float v = bufC[t * 120 + p]; s += v; s2 += v * v; }
        float m = s * (1.f / 120.f);
        float var = s2 * (1.f / 120.f) - m * m;
        meanv[t] = m; rstdv[t] = rsqrtf(var + 1e-5f);
    }
    __syncthreads();
    for (int m = t; m < 3840; m += 1024) {
        int c = m / 120;
        bufC[m] = fmaxf((bufC[m] - meanv[c]) * rstdv[c], 0.f);
    }
    __syncthreads();

    // stage3: grouped conv 32->64: flat m = c*240 + j*120 + p (7680)
    for (int m = t; m < 7680; m += 1024) {
        int c = m / 240;
        int r = m - c * 240;
        int j = r / 120;
        int p = r - j * 120;
        bufA[m] = fmaf(bufC[c * 120 + p], w3[c * 2 + j], b3[c * 2 + j]);
    }
    __syncthreads();
    // IN over view (16, 480)
    if (t < 16) {
        float s = 0.f, s2 = 0.f;
        for (int p = 0; p < 480; ++p) { float v = bufA[t * 480 + p]; s += v; s2 += v * v; }
        float m = s * (1.f / 480.f);
        float var = s2 * (1.f / 480.f) - m * m;
        meanv[t] = m; rstdv[t] = rsqrtf(var + 1e-5f);
    }
    __syncthreads();
    for (int m = t; m < 7680; m += 1024) {
        int c = m / 480;
        bufA[m] = fmaxf((bufA[m] - meanv[c]) * rstdv[c], 0.f);
    }
    __syncthreads();

    // stage4 IN stats computed analytically from x3n channel sums:
    // x4[c, j*480+p] = x3n[c,p]*w4[c,j] + b4[c*4+j]
    if (t < 16) {
        float s = 0.f, s2 = 0.f;
        for (int p = 0; p < 480; ++p) { float v = bufA[t * 480 + p]; s += v; s2 += v * v; }
        float sum4 = 0.f, sq4 = 0.f;
        for (int j = 0; j < 4; ++j) {
            float w = w4[t * 4 + j], bb = b4[t * 4 + j];
            sum4 += w * s + 480.f * bb;
            sq4  += w * w * s2 + 2.f * w * bb * s + 480.f * bb * bb;
        }
        float m = sum4 * (1.f / 1920.f);
        float var = sq4 * (1.f / 1920.f) - m * m;
        m4[t] = m; r4[t] = rsqrtf(var + 1e-5f);
    }
    __syncthreads();

    // per-point: stage4 apply + stage5 einsum + tanh + trilinear splat
    for (int l = t; l < NPT; l += 1024) {
        int j = l / 480;
        int p = l - j * 480;
        float a0 = b5[0], a1 = b5[1], a2 = b5[2];
        #pragma unroll
        for (int c = 0; c < 16; ++c) {
            float xv = bufA[c * 480 + p];
            float x4 = fmaf(xv, w4[c * 4 + j], b4[c * 4 + j]);
            float h  = fmaxf((x4 - m4[c]) * r4[c], 0.f);
            a0 = fmaf(w5[c],      h, a0);
            a1 = fmaf(w5[16 + c], h, a1);
            a2 = fmaf(w5[32 + c], h, a2);
        }
        float px = tanhf(a0) * 64.f + 63.5f;
        float py = tanhf(a1) * 64.f + 63.5f;
        float pz = tanhf(a2) * 64.f + 63.5f;
        float val = 1.f / (1.f + expf(-qval[l]));

        float x0f = floorf(px), y0f = floorf(py), z0f = floorf(pz);
        float fx = px - x0f, fy = py - y0f, fz = pz - z0f;
        int x0 = (int)x0f, y0 = (int)y0f, z0 = (int)z0f;
        for (int dz = 0; dz < 2; ++dz) {
            int zi = z0 + dz;
            if (zi < 0 || zi >= NVOX) continue;
            float wz = dz ? fz : 1.f - fz;
            for (int dy = 0; dy < 2; ++dy) {
                int yi = y0 + dy;
                if (yi < 0 || yi >= NVOX) continue;
                float wy = dy ? fy : 1.f - fy;
                for (int dx = 0; dx < 2; ++dx) {
                    int xi = x0 + dx;
                    if (xi < 0 || xi >= NVOX) continue;
                    float wx = dx ? fx : 1.f - fx;
                    float w = wx * wy * wz;
                    int idx = ((b * NVOX + zi) * NVOX + yi) * NVOX + xi;
                    atomicAdd(&acc[idx].x, w * val);
                    atomicAdd(&acc[idx].y, w);
                }
            }
        }
    }
}

// ---------------------------------------------------------------------------
// Composed smoothing: per-axis 7-tap [1,3,6,7,6,3,1]/27 with boundary rows
// row0=[4,5,3,1]/27, row1=[5,7,6,3,1]/27 (= A^3, A = zero-padded 3-tap avg).
// z/y passes: each lane handles TWO adjacent x via float4 (16 B/lane).
// ---------------------------------------------------------------------------
__device__ __forceinline__ float4 w7v(float4 v0, float4 v1, float4 v2, float4 v3,
                                      float4 v4, float4 v5, float4 v6,
                                      float cm1, float c0, float cp1)
{
    float4 r;
    r.x = ((v0.x + v6.x) + 3.f * (v1.x + v5.x) + cm1 * v2.x + c0 * v3.x + cp1 * v4.x) * (1.f / 27.f);
    r.y = ((v0.y + v6.y) + 3.f * (v1.y + v5.y) + cm1 * v2.y + c0 * v3.y + cp1 * v4.y) * (1.f / 27.f);
    r.z = ((v0.z + v6.z) + 3.f * (v1.z + v5.z) + cm1 * v2.z + c0 * v3.z + cp1 * v4.z) * (1.f / 27.f);
    r.w = ((v0.w + v6.w) + 3.f * (v1.w + v5.w) + cm1 * v2.w + c0 * v3.w + cp1 * v4.w) * (1.f / 27.f);
    return r;
}

// HI4 = per-line offset in float4 units, STEP4 = axis stride in float4 units.
// z-pass: HI4=64 (y), STEP4=8192. y-pass: HI4=8192 (z), STEP4=64.
template <int HI4, int STEP4>
__global__ __launch_bounds__(256)
void smooth_pass(const float4* __restrict__ in, float4* __restrict__ out)
{
    int T = blockIdx.x * 256 + threadIdx.x;   // 131072 threads total
    int x2 = T & 63;
    int hi = (T >> 6) & 127;
    int b  = T >> 13;
    int base = b * (VOL_PER_B / 2) + hi * HI4 + x2;
    const float4* ip = in + base;
    float4* op = out + base;

    const float4 z = make_float4(0.f, 0.f, 0.f, 0.f);
    float4 v0 = z, v1 = z, v2 = z, v3, v4, v5;
    v3 = ip[0]; v4 = ip[STEP4]; v5 = ip[2 * STEP4];

    // i = 0,1 (left boundary weights)
    {
        float4 a  = ip[3 * STEP4];
        float4 bb = ip[4 * STEP4];
        op[0]     = w7v(v0, v1, v2, v3, v4, v5, a, 6.f, 4.f, 5.f);
        op[STEP4] = w7v(v1, v2, v3, v4, v5, a, bb, 5.f, 7.f, 6.f);
        v0 = v2; v1 = v3; v2 = v4; v3 = v5; v4 = a; v5 = bb;
    }
    // interior: i = 2..122 (loads up to ip[126])
    #pragma unroll 4
    for (int i = 2; i < 124; i += 2) {
        float4 a  = ip[(i + 3) * STEP4];
        float4 bb = ip[(i + 4) * STEP4];
        op[i * STEP4]       = w7v(v0, v1, v2, v3, v4, v5, a, 6.f, 7.f, 6.f);
        op[(i + 1) * STEP4] = w7v(v1, v2, v3, v4, v5, a, bb, 6.f, 7.f, 6.f);
        v0 = v2; v1 = v3; v2 = v4; v3 = v5; v4 = a; v5 = bb;
    }
    // i = 124,125
    {
        float4 a  = ip[127 * STEP4];
        float4 bb = z;
        op[124 * STEP4] = w7v(v0, v1, v2, v3, v4, v5, a, 6.f, 7.f, 6.f);
        op[125 * STEP4] = w7v(v1, v2, v3, v4, v5, a, bb, 6.f, 7.f, 6.f);
        v0 = v2; v1 = v3; v2 = v4; v3 = v5; v4 = a; v5 = bb;
    }
    // i = 126,127 (right boundary weights)
    {
        float4 a = z, bb = z;
        op[126 * STEP4] = w7v(v0, v1, v2, v3, v4, v5, a, 6.f, 7.f, 5.f);
        op[127 * STEP4] = w7v(v1, v2, v3, v4, v5, a, bb, 5.f, 4.f, 6.f);
    }
}

// ---------------------------------------------------------------------------
// X-axis pass (contiguous) fused with the final division.
// Block = 256 threads = 4 lines of 128 float2, staged in LDS via float4 loads.
// Lane computes x=k and x=k+64 (stride-1 LDS reads -> 2 lanes/bank, free).
// ---------------------------------------------------------------------------
__global__ __launch_bounds__(256)
void smooth_x_div(const float2* __restrict__ in, float* __restrict__ out)
{
    __shared__ __align__(16) float2 lines[4][136];  // [4..131] data, pads zero
    const int t = threadIdx.x;

    // load 4 lines (256 float4 = 512 float2) cooperatively
    const float4* in4 = (const float4*)in;
    float4 v = in4[blockIdx.x * 256 + t];
    {
        int ln  = t >> 6;
        int pos = (t & 63) * 2;
        *(float4*)&lines[ln][4 + pos] = v;
    }
    if (t < 32) {
        int ly = t >> 3, j = t & 7;
        if (j < 4) lines[ly][j] = f2(0.f, 0.f);
        else       lines[ly][128 + j] = f2(0.f, 0.f);
    }
    __syncthreads();

    int w = t >> 6;       // line within block (one wave per line)
    int k = t & 63;
    int line_id = blockIdx.x * 4 + w;
    float* ob = out + line_id * 128;

    #pragma unroll
    for (int half = 0; half < 2; ++half) {
        int x = k + half * 64;
        float cm1 = 6.f, c0 = 7.f, cp1 = 6.f;
        if (x == 0)        { c0 = 4.f; cp1 = 5.f; }
        else if (x == 1)   { cm1 = 5.f; }
        else if (x == 126) { cp1 = 5.f; }
        else if (x == 127) { c0 = 4.f; cm1 = 5.f; }
        const float2* L = &lines[w][4 + x];
        float sa = (L[-3].x + L[3].x) + 3.f * (L[-2].x + L[2].x)
                 + cm1 * L[-1].x + c0 * L[0].x + cp1 * L[1].x;
        float sb = (L[-3].y + L[3].y) + 3.f * (L[-2].y + L[2].y)
                 + cm1 * L[-1].y + c0 * L[0].y + cp1 * L[1].y;
        ob[x] = (sa * (1.f / 27.f)) / (sb * (1.f / 27.f) + 0.001f);
    }
}

// ---------------------------------------------------------------------------
extern "C" void kernel_launch(void* const* d_in, const int* in_sizes, int n_in,
                              void* d_out, int out_size, void* d_ws, size_t ws_size,
                              hipStream_t stream)
{
    const float* q    = (const float*)d_in[0];
    const float* qval = (const float*)d_in[1];
    const float* w1   = (const float*)d_in[2];
    const float* b1   = (const float*)d_in[3];
    const float* w2   = (const float*)d_in[4];
    const float* b2   = (const float*)d_in[5];
    const float* w3   = (const float*)d_in[6];
    const float* b3   = (const float*)d_in[7];
    const float* w4   = (const float*)d_in[8];
    const float* b4   = (const float*)d_in[9];
    const float* w5   = (const float*)d_in[10];
    const float* b5   = (const float*)d_in[11];
    float* out = (float*)d_out;

    // ws layout: buf0 (interleaved {out,out0}, 268 MB) | buf1 (268 MB)
    float2* buf0 = (float2*)d_ws;
    float2* buf1 = buf0 + (size_t)TOTVOX;

    hipMemsetAsync(buf0, 0, (size_t)TOTVOX * sizeof(float2), stream);

    mlp_splat<<<NB, 1024, 0, stream>>>(q, qval, w1, b1, w2, b2, w3, b3,
                                       w4, b4, w5, b5, buf0);

    // z-axis pass (float4 lanes: 2 x-positions each)
    smooth_pass<64, 8192><<<131072 / 256, 256, 0, stream>>>((const float4*)buf0, (float4*)buf1);
    // y-axis pass
    smooth_pass<8192, 64><<<131072 / 256, 256, 0, stream>>>((const float4*)buf1, (float4*)buf0);
    // x-axis + division
    smooth_x_div<<<TOTVOX / 512, 256, 0, stream>>>(buf0, out);
}